// Round 2
// baseline (573.392 us; speedup 1.0000x reference)
//
#include <hip/hip_runtime.h>
#include <hip/hip_bf16.h>

// ---------------------------------------------------------------------------
// GIN encoder. Residual stream in bf16 only (ping-pong A/B).
// Fused per-layer kernel (k_layer): gather + MLP + residual.
// Round 2 change: the gather phase is a 4-stream row queue per wave --
// 4 concurrent gather streams keep ~4 independent 256B neighbor-row loads
// in flight per wave (vs ~2 before), hiding L3/HBM latency. Streams pop
// rows from the wave's 8-row queue for degree load-balancing. Main loop is
// branchless (masked accumulate, clamped addresses).
// ---------------------------------------------------------------------------

typedef short bf16x8 __attribute__((ext_vector_type(8)));
typedef unsigned short u16x8 __attribute__((ext_vector_type(8)));
typedef float f32x4 __attribute__((ext_vector_type(4)));

__device__ __forceinline__ float bs2f(unsigned short u) {
    return __uint_as_float(((unsigned)u) << 16);
}
__device__ __forceinline__ unsigned short f2bs(float f) {
    __hip_bfloat16 h = __float2bfloat16(f);
    return *reinterpret_cast<unsigned short*>(&h);
}

// packed unpack-accumulate: 8 bf16 -> 8 f32 adds with 1 shl + 1 and per pair
__device__ __forceinline__ void acc8(float* acc, u16x8 v) {
    union { u16x8 u; unsigned int w[4]; } cv;
    cv.u = v;
#pragma unroll
    for (int k = 0; k < 4; k++) {
        unsigned int d = cv.w[k];
        acc[2 * k]     += __uint_as_float(d << 16);
        acc[2 * k + 1] += __uint_as_float(d & 0xffff0000u);
    }
}

// masked variant: msk = ~0u accumulates, 0u adds +0.0f (no-op)
__device__ __forceinline__ void accm(float* acc, u16x8 v, unsigned msk) {
    union { u16x8 u; unsigned int w[4]; } cv;
    cv.u = v;
#pragma unroll
    for (int k = 0; k < 4; k++) {
        unsigned int d = cv.w[k] & msk;
        acc[2 * k]     += __uint_as_float(d << 16);
        acc[2 * k + 1] += __uint_as_float(d & 0xffff0000u);
    }
}

// ---------------- CSR build ----------------
__global__ __launch_bounds__(256) void k_hist(const int* __restrict__ dst,
                                              int* __restrict__ deg, int nE)
{
    int i = blockIdx.x * 256 + threadIdx.x;
    if (i < nE) atomicAdd(&deg[dst[i]], 1);
}

__global__ __launch_bounds__(256) void k_scanA(const int* __restrict__ deg,
                                               int* __restrict__ partials, int n)
{
    int i = blockIdx.x * 256 + threadIdx.x;
    int v = (i < n) ? deg[i] : 0;
#pragma unroll
    for (int off = 32; off >= 1; off >>= 1) v += __shfl_down(v, off, 64);
    __shared__ int ws[4];
    int wave = threadIdx.x >> 6;
    if ((threadIdx.x & 63) == 0) ws[wave] = v;
    __syncthreads();
    if (threadIdx.x == 0)
        partials[blockIdx.x] = ws[0] + ws[1] + ws[2] + ws[3];
}

__global__ __launch_bounds__(256) void k_scanC(const int* __restrict__ deg,
                                               const int* __restrict__ partials,
                                               int* __restrict__ rowptr,
                                               int* __restrict__ cursor,
                                               int n, int nb)
{
    __shared__ int sp[256];
    __shared__ int s[256];
    int t = threadIdx.x;
    int pv = (t < nb) ? partials[t] : 0;
    sp[t] = pv;
    __syncthreads();
    for (int off = 1; off < 256; off <<= 1) {
        int u = (t >= off) ? sp[t - off] : 0;
        __syncthreads();
        sp[t] += u;
        __syncthreads();
    }
    int base = (blockIdx.x == 0) ? 0 : sp[blockIdx.x - 1];
    int i = blockIdx.x * 256 + t;
    int v = (i < n) ? deg[i] : 0;
    s[t] = v;
    __syncthreads();
    for (int off = 1; off < 256; off <<= 1) {
        int u = (t >= off) ? s[t - off] : 0;
        __syncthreads();
        s[t] += u;
        __syncthreads();
    }
    int inc = s[t];
    if (i < n) {
        int ex = base + inc - v;
        rowptr[i] = ex;
        cursor[i] = ex;
        if (i == n - 1) rowptr[n] = base + inc;
    }
}

__global__ __launch_bounds__(256) void k_fill(const int* __restrict__ src,
                                              const int* __restrict__ dst,
                                              int* __restrict__ cursor,
                                              int* __restrict__ adj, int nE)
{
    int i = blockIdx.x * 256 + threadIdx.x;
    if (i < nE) {
        int pos = atomicAdd(&cursor[dst[i]], 1);
        adj[pos] = src[i];
    }
}

// ---------------- weight packing (all weights, one launch) ----------------
__device__ __forceinline__ void pack_one(const float* __restrict__ W,
                                         short* __restrict__ P,
                                         int id, int Kt, int Nt)
{
    int lane = id & 63;
    int t = id >> 6;
    int kt = t % Kt; t /= Kt;
    int nt = t % Nt; int l = t / Nt;
    int K = Kt * 32, N = Nt * 16;
    const float* Wl = W + (size_t)l * K * N;
    int n = nt * 16 + (lane & 15);
    int kbase = kt * 32 + (lane >> 4) * 8;
    bf16x8 v;
#pragma unroll
    for (int j = 0; j < 8; j++)
        v[j] = (short)f2bs(Wl[(size_t)(kbase + j) * N + n]);
    *(bf16x8*)(P + (size_t)id * 8) = v;
}

#define PK1 16384   // 4 layers * Nt16 * Kt4 * 64
#define PK2 16384   // 4 layers * Nt8  * Kt8 * 64
#define PK0 2048    // 1 layer  * Nt8  * Kt4 * 64

__global__ __launch_bounds__(256) void k_pack_all(
    const float* __restrict__ mlpW1, const float* __restrict__ mlpW2,
    const float* __restrict__ W0,
    short* __restrict__ pW1, short* __restrict__ pW2, short* __restrict__ pW0)
{
    int id = blockIdx.x * 256 + threadIdx.x;
    if (id < PK1) {
        pack_one(mlpW1, pW1, id, 4, 16);
    } else if (id < PK1 + PK2) {
        pack_one(mlpW2, pW2, id - PK1, 8, 8);
    } else if (id < PK1 + PK2 + PK0) {
        pack_one(W0, pW0, id - PK1 - PK2, 4, 8);
    }
}

// ---------------- encoder: hb = bf16(x@W0 + b0) via MFMA ------------------
__global__ __launch_bounds__(256) void k_encoder(const float* __restrict__ x,
                                                 const short* __restrict__ pW0,
                                                 const float* __restrict__ b0,
                                                 unsigned short* __restrict__ hb,
                                                 int n)
{
    __shared__ unsigned short sX[32][136];
    const int t = threadIdx.x;
    const int w = t >> 6;
    const int L = t & 63;
    const int node0 = blockIdx.x * 32;

    const float4* x4 = (const float4*)x;
    for (int i = t; i < 32 * 32; i += 256) {
        int m = i >> 5, cgi = i & 31;
        int node = node0 + m;
        float4 v = make_float4(0.f, 0.f, 0.f, 0.f);
        if (node < n) v = x4[(size_t)node * 32 + cgi];
        ushort4 p;
        p.x = f2bs(v.x); p.y = f2bs(v.y); p.z = f2bs(v.z); p.w = f2bs(v.w);
        *(ushort4*)&sX[m][cgi * 4] = p;
    }
    __syncthreads();

    const int quad = L >> 4;
    const int l16 = L & 15;
    const bf16x8* base = (const bf16x8*)pW0;

#pragma unroll
    for (int jj = 0; jj < 2; jj++) {
        int nt = w * 2 + jj;
        bf16x8 b[4];
#pragma unroll
        for (int kt = 0; kt < 4; kt++)
            b[kt] = base[(size_t)(nt * 4 + kt) * 64 + L];
        int c = nt * 16 + l16;
        float bc = b0[c];
#pragma unroll
        for (int hh = 0; hh < 2; hh++) {
            int mh = hh * 16;
            f32x4 acc = {0.f, 0.f, 0.f, 0.f};
#pragma unroll
            for (int kt = 0; kt < 4; kt++) {
                bf16x8 a = *(const bf16x8*)&sX[mh + l16][kt * 32 + quad * 8];
                acc = __builtin_amdgcn_mfma_f32_16x16x32_bf16(a, b[kt], acc, 0, 0, 0);
            }
#pragma unroll
            for (int r = 0; r < 4; r++) {
                int node = node0 + mh + quad * 4 + r;
                if (node < n)
                    hb[(size_t)node * 128 + c] = f2bs(acc[r] + bc);
            }
        }
    }
}

// ---------------- fused layer: gather + MLP + residual --------------------
// hb_out = hb_in + relu(BN2(W2 relu(BN1(W1 (hb_in + sum_neighbors)))))
// Gather: 4-stream row queue per wave (see header comment).
// Lane layout: g = L>>4 selects one of 4 edges per chunk, l16 = L&15 is the
// 16B channel segment; a group of 16 lanes loads one full 256B node row.
__global__ __launch_bounds__(256, 6) void k_layer(
    const unsigned short* __restrict__ hb_in,
    unsigned short* __restrict__ hb_out,
    const int* __restrict__ rowptr, const int* __restrict__ adj,
    const short* __restrict__ pW1, const float* __restrict__ b1,
    const float* __restrict__ g1, const float* __restrict__ be1,
    const float* __restrict__ mu1, const float* __restrict__ va1,
    const short* __restrict__ pW2, const float* __restrict__ b2,
    const float* __restrict__ g2, const float* __restrict__ be2,
    const float* __restrict__ mu2, const float* __restrict__ va2,
    int n)
{
    __shared__ unsigned short sIn[32][136];    // gathered agg; reused for m out
    __shared__ unsigned short sMid[32][264];   // bf16 MLP hidden, pad 8
    const int t = threadIdx.x;
    const int w = t >> 6;
    const int L = t & 63;
    const int node0 = blockIdx.x * 32;
    const int g = L >> 4;
    const int l16 = L & 15;
    const int wrow = w * 8;

    // ---- gather phase: wave w fills sIn rows wrow..wrow+7 ----
    {
        const u16x8* hb8 = (const u16x8*)hb_in;
        int nextRow = 4;

        float accA[8], accB[8], accC[8], accD[8];
        u16x8 selfA, selfB, selfC, selfD;
        int rowA = 0, rowB = 1, rowC = 2, rowD = 3;
        int eA = 0, eB = 0, eC = 0, eD = 0;
        int qA = 0, qB = 0, qC = 0, qD = 0;
        bool alA, alB, alC, alD;

        // pop a row off the queue: init stream state; zero-fill invalid rows
        auto popRow = [&](int& row, int& e, int& q, u16x8& self,
                          float* acc) -> bool {
            for (;;) {
                if (row >= 8) return false;
                int node = node0 + wrow + row;
                if (node < n) {
                    e = rowptr[node];
                    q = rowptr[node + 1];
                    self = hb8[(unsigned)node * 16u + l16];
#pragma unroll
                    for (int j = 0; j < 8; j++) acc[j] = 0.f;
                    return true;
                }
                if (g == 0) {
                    u16x8 z;
#pragma unroll
                    for (int j = 0; j < 8; j++) z[j] = 0;
                    *(u16x8*)&sIn[wrow + row][l16 * 8] = z;
                }
                row = nextRow++;
            }
        };

        alA = popRow(rowA, eA, qA, selfA, accA);
        alB = popRow(rowB, eB, qB, selfB, accB);
        alC = popRow(rowC, eC, qC, selfC, accC);
        alD = popRow(rowD, eD, qD, selfD, accD);

// finish row: reduce 4 edge groups, add self, write LDS, pop next row
#define FIN(S)                                                              \
        {                                                                   \
            u16x8 o;                                                        \
            _Pragma("unroll")                                               \
            for (int j = 0; j < 8; j++) {                                   \
                float vv = acc##S[j];                                       \
                vv += __shfl_xor(vv, 16, 64);                               \
                vv += __shfl_xor(vv, 32, 64);                               \
                o[j] = f2bs(vv + bs2f(self##S[j]));                         \
            }                                                               \
            if (g == 0)                                                     \
                *(u16x8*)&sIn[wrow + row##S][l16 * 8] = o;                  \
            row##S = nextRow++;                                             \
            al##S = popRow(row##S, e##S, q##S, self##S, acc##S);            \
        }

        while (alA || alB || alC || alD) {
            bool okA = alA && (eA < qA);
            bool okB = alB && (eB < qB);
            bool okC = alC && (eC < qC);
            bool okD = alD && (eD < qD);
            // clamped in-bounds addresses; per-lane validity in the mask
            int xA = eA + g, xB = eB + g, xC = eC + g, xD = eD + g;
            int aAi = okA ? (xA < qA ? xA : qA - 1) : g;
            int aBi = okB ? (xB < qB ? xB : qB - 1) : g;
            int aCi = okC ? (xC < qC ? xC : qC - 1) : g;
            int aDi = okD ? (xD < qD ? xD : qD - 1) : g;
            int iA = adj[aAi];
            int iB = adj[aBi];
            int iC = adj[aCi];
            int iD = adj[aDi];
            u16x8 vA = hb8[(unsigned)iA * 16u + l16];
            u16x8 vB = hb8[(unsigned)iB * 16u + l16];
            u16x8 vC = hb8[(unsigned)iC * 16u + l16];
            u16x8 vD = hb8[(unsigned)iD * 16u + l16];
            accm(accA, vA, (okA && xA < qA) ? ~0u : 0u);
            accm(accB, vB, (okB && xB < qB) ? ~0u : 0u);
            accm(accC, vC, (okC && xC < qC) ? ~0u : 0u);
            accm(accD, vD, (okD && xD < qD) ? ~0u : 0u);
            eA += okA ? 4 : 0;
            eB += okB ? 4 : 0;
            eC += okC ? 4 : 0;
            eD += okD ? 4 : 0;
            if (alA && eA >= qA) FIN(A)
            if (alB && eB >= qB) FIN(B)
            if (alC && eC >= qC) FIN(C)
            if (alD && eD >= qD) FIN(D)
        }
#undef FIN
    }
    __syncthreads();

    const int quad = L >> 4;

    // ---- phase 1: sMid = relu(BN1(sIn @ W1 + b1)), 32x256, K=128 ----
    {
        const bf16x8* base1 = (const bf16x8*)pW1;
#pragma unroll
        for (int j = 0; j < 4; j++) {
            int nt = w * 4 + j;
            bf16x8 b[4];
#pragma unroll
            for (int kt = 0; kt < 4; kt++)
                b[kt] = base1[(size_t)(nt * 4 + kt) * 64 + L];
            int c = nt * 16 + l16;
            float sc = g1[c] * rsqrtf(va1[c] + 1e-5f);
            float sh = (b1[c] - mu1[c]) * sc + be1[c];
#pragma unroll
            for (int hh = 0; hh < 2; hh++) {
                int mh = hh * 16;
                f32x4 acc = {0.f, 0.f, 0.f, 0.f};
#pragma unroll
                for (int kt = 0; kt < 4; kt++) {
                    bf16x8 a = *(const bf16x8*)&sIn[mh + l16][kt * 32 + quad * 8];
                    acc = __builtin_amdgcn_mfma_f32_16x16x32_bf16(a, b[kt], acc, 0, 0, 0);
                }
#pragma unroll
                for (int r = 0; r < 4; r++) {
                    float v = fmaxf(acc[r] * sc + sh, 0.f);
                    sMid[mh + quad * 4 + r][c] = f2bs(v);
                }
            }
        }
    }
    __syncthreads();

    // ---- phase 2: m = relu(BN2(sMid @ W2 + b2)) -> staged into sIn ----
    {
        const bf16x8* base2 = (const bf16x8*)pW2;
#pragma unroll
        for (int jj = 0; jj < 2; jj++) {
            int nt = w * 2 + jj;
            f32x4 acc[2];
            acc[0] = (f32x4){0.f, 0.f, 0.f, 0.f};
            acc[1] = (f32x4){0.f, 0.f, 0.f, 0.f};
#pragma unroll
            for (int kh = 0; kh < 2; kh++) {
                bf16x8 b[4];
#pragma unroll
                for (int kt = 0; kt < 4; kt++)
                    b[kt] = base2[(size_t)(nt * 8 + kh * 4 + kt) * 64 + L];
#pragma unroll
                for (int hh = 0; hh < 2; hh++) {
                    int mh = hh * 16;
#pragma unroll
                    for (int kt = 0; kt < 4; kt++) {
                        bf16x8 a = *(const bf16x8*)&sMid[mh + l16][(kh * 4 + kt) * 32 + quad * 8];
                        acc[hh] = __builtin_amdgcn_mfma_f32_16x16x32_bf16(a, b[kt], acc[hh], 0, 0, 0);
                    }
                }
            }
            int c = nt * 16 + l16;
            float sc = g2[c] * rsqrtf(va2[c] + 1e-5f);
            float sh = (b2[c] - mu2[c]) * sc + be2[c];
#pragma unroll
            for (int hh = 0; hh < 2; hh++) {
#pragma unroll
                for (int r = 0; r < 4; r++) {
                    float o = fmaxf(acc[hh][r] * sc + sh, 0.f);
                    sIn[hh * 16 + quad * 4 + r][c] = f2bs(o);
                }
            }
        }
    }
    __syncthreads();

    // ---- coalesced epilogue: hb_out = hb_in + m (16 B/lane streams) ----
    {
        const u16x8* hs8 = (const u16x8*)hb_in;
#pragma unroll
        for (int idx = t; idx < 512; idx += 256) {
            int row = idx >> 4, seg = idx & 15;
            int node = node0 + row;
            if (node < n) {
                u16x8 m = *(const u16x8*)&sIn[row][seg * 8];
                u16x8 s = hs8[(size_t)node * 16 + seg];
                u16x8 o;
#pragma unroll
                for (int j = 0; j < 8; j++)
                    o[j] = f2bs(bs2f(s[j]) + bs2f(m[j]));
                *(u16x8*)(hb_out + (size_t)node * 128 + seg * 8) = o;
            }
        }
    }
}

// ---------------- pooling: run-length over sorted batch (bf16 in) ---------
// 16-node runs -> ~1563 blocks (~6/CU) so the serial load chain is short.
__global__ __launch_bounds__(256) void k_pool(const unsigned short* __restrict__ hb,
                                              const int* __restrict__ batch,
                                              float* __restrict__ pooled, int n)
{
    int c = threadIdx.x & 127;
    int half = threadIdx.x >> 7;
    int base = blockIdx.x * 32 + half * 16;
    float acc = 0.f;
    int curg = -1;
    for (int i = 0; i < 16; i++) {
        int node = base + i;
        if (node >= n) break;
        int g = batch[node];
        if (g != curg) {
            if (curg >= 0) atomicAdd(&pooled[(size_t)curg * 128 + c], acc);
            curg = g;
            acc = 0.f;
        }
        acc += bs2f(hb[(size_t)node * 128 + c]);
    }
    if (curg >= 0) atomicAdd(&pooled[(size_t)curg * 128 + c], acc);
}

__global__ __launch_bounds__(128) void k_head(const float* __restrict__ pooled,
                                              const float* __restrict__ W1,
                                              const float* __restrict__ b1,
                                              const float* __restrict__ W2,
                                              const float* __restrict__ b2,
                                              float* __restrict__ out)
{
    __shared__ float sp[128];
    __shared__ float st[128];
    int t = threadIdx.x;
    int g = blockIdx.x;
    sp[t] = pooled[(size_t)g * 128 + t];
    __syncthreads();
    float a = 0.f;
    for (int k = 0; k < 128; k++) a += sp[k] * W1[k * 128 + t];
    st[t] = fmaxf(a + b1[t], 0.f);
    __syncthreads();
    float o = 0.f;
    for (int k = 0; k < 128; k++) o += st[k] * W2[k * 128 + t];
    out[(size_t)g * 128 + t] = o + b2[t];
}

extern "C" void kernel_launch(void* const* d_in, const int* in_sizes, int n_in,
                              void* d_out, int out_size, void* d_ws, size_t ws_size,
                              hipStream_t stream)
{
    const float* x     = (const float*)d_in[0];
    const int*   ei    = (const int*)d_in[1];
    const int*   batch = (const int*)d_in[2];
    const float* W0    = (const float*)d_in[3];
    const float* b0    = (const float*)d_in[4];
    const float* mlpW1 = (const float*)d_in[5];
    const float* mlpb1 = (const float*)d_in[6];
    const float* bn1g  = (const float*)d_in[7];
    const float* bn1b  = (const float*)d_in[8];
    const float* bn1m  = (const float*)d_in[9];
    const float* bn1v  = (const float*)d_in[10];
    const float* mlpW2 = (const float*)d_in[11];
    const float* mlpb2 = (const float*)d_in[12];
    const float* ng    = (const float*)d_in[13];
    const float* nb    = (const float*)d_in[14];
    const float* nm    = (const float*)d_in[15];
    const float* nv    = (const float*)d_in[16];
    const float* W1    = (const float*)d_in[17];
    const float* b1    = (const float*)d_in[18];
    const float* W2    = (const float*)d_in[19];
    const float* b2    = (const float*)d_in[20];
    float* out = (float*)d_out;

    const int N = in_sizes[0] / 128;
    const int E = in_sizes[1] / 2;
    const int G = out_size / 128;
    const int* srcv = ei;
    const int* dstv = ei + E;

    // workspace layout
    float* pooled = (float*)d_ws;                               // G*128 f32
    unsigned short* hbA = (unsigned short*)(pooled + (size_t)G * 128); // N*128
    unsigned short* hbB = hbA + (size_t)N * 128;                // N*128
    short* pW1 = (short*)(hbB + (size_t)N * 128);               // 4*128*256
    short* pW2 = pW1 + 131072;                                  // 4*256*128
    short* pW0 = pW2 + 131072;                                  // 128*128
    int* ints  = (int*)(pW0 + 16384);
    int* deg      = ints;
    int* rowptr   = ints + N;
    int* cursor   = ints + 2 * N + 1;
    int* partials = ints + 3 * N + 1;                           // 256
    int* adj      = ints + 3 * N + 1 + 256;                     // E

    const int nodeBlocks = (N + 31) / 32;
    const int nbScan = (N + 255) / 256;

    // ---- CSR build + weight packing ----
    hipMemsetAsync(deg, 0, (size_t)N * sizeof(int), stream);
    k_hist<<<(E + 255) / 256, 256, 0, stream>>>(dstv, deg, E);
    k_scanA<<<nbScan, 256, 0, stream>>>(deg, partials, N);
    k_scanC<<<nbScan, 256, 0, stream>>>(deg, partials, rowptr, cursor, N, nbScan);
    k_fill<<<(E + 255) / 256, 256, 0, stream>>>(srcv, dstv, cursor, adj, E);
    k_pack_all<<<(PK1 + PK2 + PK0 + 255) / 256, 256, 0, stream>>>(
        mlpW1, mlpW2, W0, pW1, pW2, pW0);

    // ---- encoder ----
    k_encoder<<<nodeBlocks, 256, 0, stream>>>(x, pW0, b0, hbA, N);

    // ---- layers: fused gather+MLP, ping-pong hbA/hbB ----
    unsigned short* hc = hbA;
    unsigned short* hn = hbB;
    for (int l = 0; l < 4; l++) {
        k_layer<<<nodeBlocks, 256, 0, stream>>>(
            hc, hn, rowptr, adj,
            pW1 + (size_t)l * 32768, mlpb1 + (size_t)l * 256,
            bn1g + (size_t)l * 256, bn1b + (size_t)l * 256,
            bn1m + (size_t)l * 256, bn1v + (size_t)l * 256,
            pW2 + (size_t)l * 32768, mlpb2 + (size_t)l * 128,
            ng + (size_t)l * 128, nb + (size_t)l * 128,
            nm + (size_t)l * 128, nv + (size_t)l * 128,
            N);
        unsigned short* tmp = hc; hc = hn; hn = tmp;
    }

    // ---- pool + head ----
    hipMemsetAsync(pooled, 0, (size_t)G * 128 * sizeof(float), stream);
    k_pool<<<(N + 31) / 32, 256, 0, stream>>>(hc, batch, pooled, N);
    k_head<<<G, 128, 0, stream>>>(pooled, W1, b1, W2, b2, out);
}

// Round 3
// 380.680 us; speedup vs baseline: 1.5062x; 1.5062x over previous
//
#include <hip/hip_runtime.h>
#include <hip/hip_bf16.h>

// ---------------------------------------------------------------------------
// GIN encoder. Residual stream in bf16 only (ping-pong A/B).
// Fused per-layer kernel (k_layer): gather + MLP + residual.
// Round 3: gather uses TWO STATIC streams per wave (rows i and i+4),
// wave-uniform control flow, clamped+masked chunk loads, and software-
// pipelined adj prefetch. All accumulators in named, statically-indexed
// arrays (no address escape -> no scratch; round 2's queue version spilled
// ~175MB/dispatch to scratch via a pointer-taking lambda).
// ---------------------------------------------------------------------------

typedef short bf16x8 __attribute__((ext_vector_type(8)));
typedef unsigned short u16x8 __attribute__((ext_vector_type(8)));
typedef float f32x4 __attribute__((ext_vector_type(4)));

__device__ __forceinline__ float bs2f(unsigned short u) {
    return __uint_as_float(((unsigned)u) << 16);
}
__device__ __forceinline__ unsigned short f2bs(float f) {
    __hip_bfloat16 h = __float2bfloat16(f);
    return *reinterpret_cast<unsigned short*>(&h);
}

// masked packed unpack-accumulate: msk=~0u accumulates, 0u adds +0.0f
__device__ __forceinline__ void accm(float* acc, u16x8 v, unsigned msk) {
    union { u16x8 u; unsigned int w[4]; } cv;
    cv.u = v;
#pragma unroll
    for (int k = 0; k < 4; k++) {
        unsigned int d = cv.w[k] & msk;
        acc[2 * k]     += __uint_as_float(d << 16);
        acc[2 * k + 1] += __uint_as_float(d & 0xffff0000u);
    }
}

// ---------------- CSR build ----------------
__global__ __launch_bounds__(256) void k_hist(const int* __restrict__ dst,
                                              int* __restrict__ deg, int nE)
{
    int i = blockIdx.x * 256 + threadIdx.x;
    if (i < nE) atomicAdd(&deg[dst[i]], 1);
}

__global__ __launch_bounds__(256) void k_scanA(const int* __restrict__ deg,
                                               int* __restrict__ partials, int n)
{
    int i = blockIdx.x * 256 + threadIdx.x;
    int v = (i < n) ? deg[i] : 0;
#pragma unroll
    for (int off = 32; off >= 1; off >>= 1) v += __shfl_down(v, off, 64);
    __shared__ int ws[4];
    int wave = threadIdx.x >> 6;
    if ((threadIdx.x & 63) == 0) ws[wave] = v;
    __syncthreads();
    if (threadIdx.x == 0)
        partials[blockIdx.x] = ws[0] + ws[1] + ws[2] + ws[3];
}

__global__ __launch_bounds__(256) void k_scanC(const int* __restrict__ deg,
                                               const int* __restrict__ partials,
                                               int* __restrict__ rowptr,
                                               int* __restrict__ cursor,
                                               int n, int nb)
{
    __shared__ int sp[256];
    __shared__ int s[256];
    int t = threadIdx.x;
    int pv = (t < nb) ? partials[t] : 0;
    sp[t] = pv;
    __syncthreads();
    for (int off = 1; off < 256; off <<= 1) {
        int u = (t >= off) ? sp[t - off] : 0;
        __syncthreads();
        sp[t] += u;
        __syncthreads();
    }
    int base = (blockIdx.x == 0) ? 0 : sp[blockIdx.x - 1];
    int i = blockIdx.x * 256 + t;
    int v = (i < n) ? deg[i] : 0;
    s[t] = v;
    __syncthreads();
    for (int off = 1; off < 256; off <<= 1) {
        int u = (t >= off) ? s[t - off] : 0;
        __syncthreads();
        s[t] += u;
        __syncthreads();
    }
    int inc = s[t];
    if (i < n) {
        int ex = base + inc - v;
        rowptr[i] = ex;
        cursor[i] = ex;
        if (i == n - 1) rowptr[n] = base + inc;
    }
}

__global__ __launch_bounds__(256) void k_fill(const int* __restrict__ src,
                                              const int* __restrict__ dst,
                                              int* __restrict__ cursor,
                                              int* __restrict__ adj, int nE)
{
    int i = blockIdx.x * 256 + threadIdx.x;
    if (i < nE) {
        int pos = atomicAdd(&cursor[dst[i]], 1);
        adj[pos] = src[i];
    }
}

// ---------------- weight packing (all weights, one launch) ----------------
__device__ __forceinline__ void pack_one(const float* __restrict__ W,
                                         short* __restrict__ P,
                                         int id, int Kt, int Nt)
{
    int lane = id & 63;
    int t = id >> 6;
    int kt = t % Kt; t /= Kt;
    int nt = t % Nt; int l = t / Nt;
    int K = Kt * 32, N = Nt * 16;
    const float* Wl = W + (size_t)l * K * N;
    int n = nt * 16 + (lane & 15);
    int kbase = kt * 32 + (lane >> 4) * 8;
    bf16x8 v;
#pragma unroll
    for (int j = 0; j < 8; j++)
        v[j] = (short)f2bs(Wl[(size_t)(kbase + j) * N + n]);
    *(bf16x8*)(P + (size_t)id * 8) = v;
}

#define PK1 16384   // 4 layers * Nt16 * Kt4 * 64
#define PK2 16384   // 4 layers * Nt8  * Kt8 * 64
#define PK0 2048    // 1 layer  * Nt8  * Kt4 * 64

__global__ __launch_bounds__(256) void k_pack_all(
    const float* __restrict__ mlpW1, const float* __restrict__ mlpW2,
    const float* __restrict__ W0,
    short* __restrict__ pW1, short* __restrict__ pW2, short* __restrict__ pW0)
{
    int id = blockIdx.x * 256 + threadIdx.x;
    if (id < PK1) {
        pack_one(mlpW1, pW1, id, 4, 16);
    } else if (id < PK1 + PK2) {
        pack_one(mlpW2, pW2, id - PK1, 8, 8);
    } else if (id < PK1 + PK2 + PK0) {
        pack_one(W0, pW0, id - PK1 - PK2, 4, 8);
    }
}

// ---------------- encoder: hb = bf16(x@W0 + b0) via MFMA ------------------
__global__ __launch_bounds__(256) void k_encoder(const float* __restrict__ x,
                                                 const short* __restrict__ pW0,
                                                 const float* __restrict__ b0,
                                                 unsigned short* __restrict__ hb,
                                                 int n)
{
    __shared__ unsigned short sX[32][136];
    const int t = threadIdx.x;
    const int w = t >> 6;
    const int L = t & 63;
    const int node0 = blockIdx.x * 32;

    const float4* x4 = (const float4*)x;
    for (int i = t; i < 32 * 32; i += 256) {
        int m = i >> 5, cgi = i & 31;
        int node = node0 + m;
        float4 v = make_float4(0.f, 0.f, 0.f, 0.f);
        if (node < n) v = x4[(size_t)node * 32 + cgi];
        ushort4 p;
        p.x = f2bs(v.x); p.y = f2bs(v.y); p.z = f2bs(v.z); p.w = f2bs(v.w);
        *(ushort4*)&sX[m][cgi * 4] = p;
    }
    __syncthreads();

    const int quad = L >> 4;
    const int l16 = L & 15;
    const bf16x8* base = (const bf16x8*)pW0;

#pragma unroll
    for (int jj = 0; jj < 2; jj++) {
        int nt = w * 2 + jj;
        bf16x8 b[4];
#pragma unroll
        for (int kt = 0; kt < 4; kt++)
            b[kt] = base[(size_t)(nt * 4 + kt) * 64 + L];
        int c = nt * 16 + l16;
        float bc = b0[c];
#pragma unroll
        for (int hh = 0; hh < 2; hh++) {
            int mh = hh * 16;
            f32x4 acc = {0.f, 0.f, 0.f, 0.f};
#pragma unroll
            for (int kt = 0; kt < 4; kt++) {
                bf16x8 a = *(const bf16x8*)&sX[mh + l16][kt * 32 + quad * 8];
                acc = __builtin_amdgcn_mfma_f32_16x16x32_bf16(a, b[kt], acc, 0, 0, 0);
            }
#pragma unroll
            for (int r = 0; r < 4; r++) {
                int node = node0 + mh + quad * 4 + r;
                if (node < n)
                    hb[(size_t)node * 128 + c] = f2bs(acc[r] + bc);
            }
        }
    }
}

// ---------------- fused layer: gather + MLP + residual --------------------
// hb_out = hb_in + relu(BN2(W2 relu(BN1(W1 (hb_in + sum_neighbors)))))
// Gather: 2 static streams/wave (rows i, i+4), clamped+masked 4-edge chunks,
// unroll-2 per stream, adj prefetched one iteration ahead. Lane layout:
// g = L>>4 picks 1 of 4 edges in the chunk, l16 = L&15 is the 16B segment;
// 16 lanes cover one 256B node row.
__global__ __launch_bounds__(256, 6) void k_layer(
    const unsigned short* __restrict__ hb_in,
    unsigned short* __restrict__ hb_out,
    const int* __restrict__ rowptr, const int* __restrict__ adj,
    const short* __restrict__ pW1, const float* __restrict__ b1,
    const float* __restrict__ g1, const float* __restrict__ be1,
    const float* __restrict__ mu1, const float* __restrict__ va1,
    const short* __restrict__ pW2, const float* __restrict__ b2,
    const float* __restrict__ g2, const float* __restrict__ be2,
    const float* __restrict__ mu2, const float* __restrict__ va2,
    int n)
{
    __shared__ unsigned short sIn[32][136];    // gathered agg; reused for m out
    __shared__ unsigned short sMid[32][264];   // bf16 MLP hidden, pad 8
    const int t = threadIdx.x;
    const int w = t >> 6;
    const int L = t & 63;
    const int node0 = blockIdx.x * 32;
    const int g = L >> 4;
    const int l16 = L & 15;
    const int wrow = w * 8;

    // ---- gather phase: wave w fills sIn rows wrow..wrow+7 ----
    {
        const u16x8* hb8 = (const u16x8*)hb_in;
#pragma unroll 1
        for (int i = 0; i < 4; i++) {
            const int rowA = wrow + i;
            const int rowB = wrow + i + 4;
            const int nodeA = node0 + rowA;
            const int nodeB = node0 + rowB;
            const bool vA = nodeA < n;
            const bool vB = nodeB < n;
            int eA = 0, qA = 0, eB = 0, qB = 0;
            u16x8 selfA, selfB;
#pragma unroll
            for (int j = 0; j < 8; j++) { selfA[j] = 0; selfB[j] = 0; }
            if (vA) {
                eA = rowptr[nodeA]; qA = rowptr[nodeA + 1];
                selfA = hb8[(unsigned)nodeA * 16u + l16];
            }
            if (vB) {
                eB = rowptr[nodeB]; qB = rowptr[nodeB + 1];
                selfB = hb8[(unsigned)nodeB * 16u + l16];
            }
            float accA[8] = {0.f, 0.f, 0.f, 0.f, 0.f, 0.f, 0.f, 0.f};
            float accB[8] = {0.f, 0.f, 0.f, 0.f, 0.f, 0.f, 0.f, 0.f};

            bool okA = eA < qA, okB = eB < qB;
            int xA0 = eA + g, xA1 = eA + 4 + g;
            int iA0 = adj[okA ? (xA0 < qA ? xA0 : qA - 1) : 0];
            int iA1 = adj[okA ? (xA1 < qA ? xA1 : qA - 1) : 0];
            int xB0 = eB + g, xB1 = eB + 4 + g;
            int iB0 = adj[okB ? (xB0 < qB ? xB0 : qB - 1) : 0];
            int iB1 = adj[okB ? (xB1 < qB ? xB1 : qB - 1) : 0];

            while (okA || okB) {
                // row loads for current chunk (indices ready from last iter)
                u16x8 rA0 = hb8[(unsigned)iA0 * 16u + l16];
                u16x8 rA1 = hb8[(unsigned)iA1 * 16u + l16];
                u16x8 rB0 = hb8[(unsigned)iB0 * 16u + l16];
                u16x8 rB1 = hb8[(unsigned)iB1 * 16u + l16];
                unsigned mA0 = (okA && eA + g < qA)     ? ~0u : 0u;
                unsigned mA1 = (okA && eA + 4 + g < qA) ? ~0u : 0u;
                unsigned mB0 = (okB && eB + g < qB)     ? ~0u : 0u;
                unsigned mB1 = (okB && eB + 4 + g < qB) ? ~0u : 0u;
                // prefetch next chunk's adj while rows are in flight
                int neA = okA ? eA + 8 : eA;
                int neB = okB ? eB + 8 : eB;
                bool nokA = neA < qA, nokB = neB < qB;
                int nxA0 = neA + g, nxA1 = neA + 4 + g;
                int niA0 = adj[nokA ? (nxA0 < qA ? nxA0 : qA - 1) : 0];
                int niA1 = adj[nokA ? (nxA1 < qA ? nxA1 : qA - 1) : 0];
                int nxB0 = neB + g, nxB1 = neB + 4 + g;
                int niB0 = adj[nokB ? (nxB0 < qB ? nxB0 : qB - 1) : 0];
                int niB1 = adj[nokB ? (nxB1 < qB ? nxB1 : qB - 1) : 0];
                accm(accA, rA0, mA0);
                accm(accA, rA1, mA1);
                accm(accB, rB0, mB0);
                accm(accB, rB1, mB1);
                eA = neA; eB = neB; okA = nokA; okB = nokB;
                iA0 = niA0; iA1 = niA1; iB0 = niB0; iB1 = niB1;
            }

            // finish stream A: reduce 4 edge groups, add self, write LDS
            if (vA) {
                u16x8 o;
#pragma unroll
                for (int j = 0; j < 8; j++) {
                    float vv = accA[j];
                    vv += __shfl_xor(vv, 16, 64);
                    vv += __shfl_xor(vv, 32, 64);
                    o[j] = f2bs(vv + bs2f(selfA[j]));
                }
                if (g == 0) *(u16x8*)&sIn[rowA][l16 * 8] = o;
            } else if (g == 0) {
                u16x8 z;
#pragma unroll
                for (int j = 0; j < 8; j++) z[j] = 0;
                *(u16x8*)&sIn[rowA][l16 * 8] = z;
            }
            // finish stream B
            if (vB) {
                u16x8 o;
#pragma unroll
                for (int j = 0; j < 8; j++) {
                    float vv = accB[j];
                    vv += __shfl_xor(vv, 16, 64);
                    vv += __shfl_xor(vv, 32, 64);
                    o[j] = f2bs(vv + bs2f(selfB[j]));
                }
                if (g == 0) *(u16x8*)&sIn[rowB][l16 * 8] = o;
            } else if (g == 0) {
                u16x8 z;
#pragma unroll
                for (int j = 0; j < 8; j++) z[j] = 0;
                *(u16x8*)&sIn[rowB][l16 * 8] = z;
            }
        }
    }
    __syncthreads();

    const int quad = L >> 4;

    // ---- phase 1: sMid = relu(BN1(sIn @ W1 + b1)), 32x256, K=128 ----
    {
        const bf16x8* base1 = (const bf16x8*)pW1;
#pragma unroll
        for (int j = 0; j < 4; j++) {
            int nt = w * 4 + j;
            bf16x8 b[4];
#pragma unroll
            for (int kt = 0; kt < 4; kt++)
                b[kt] = base1[(size_t)(nt * 4 + kt) * 64 + L];
            int c = nt * 16 + l16;
            float sc = g1[c] * rsqrtf(va1[c] + 1e-5f);
            float sh = (b1[c] - mu1[c]) * sc + be1[c];
#pragma unroll
            for (int hh = 0; hh < 2; hh++) {
                int mh = hh * 16;
                f32x4 acc = {0.f, 0.f, 0.f, 0.f};
#pragma unroll
                for (int kt = 0; kt < 4; kt++) {
                    bf16x8 a = *(const bf16x8*)&sIn[mh + l16][kt * 32 + quad * 8];
                    acc = __builtin_amdgcn_mfma_f32_16x16x32_bf16(a, b[kt], acc, 0, 0, 0);
                }
#pragma unroll
                for (int r = 0; r < 4; r++) {
                    float v = fmaxf(acc[r] * sc + sh, 0.f);
                    sMid[mh + quad * 4 + r][c] = f2bs(v);
                }
            }
        }
    }
    __syncthreads();

    // ---- phase 2: m = relu(BN2(sMid @ W2 + b2)) -> staged into sIn ----
    {
        const bf16x8* base2 = (const bf16x8*)pW2;
#pragma unroll
        for (int jj = 0; jj < 2; jj++) {
            int nt = w * 2 + jj;
            f32x4 acc[2];
            acc[0] = (f32x4){0.f, 0.f, 0.f, 0.f};
            acc[1] = (f32x4){0.f, 0.f, 0.f, 0.f};
#pragma unroll
            for (int kh = 0; kh < 2; kh++) {
                bf16x8 b[4];
#pragma unroll
                for (int kt = 0; kt < 4; kt++)
                    b[kt] = base2[(size_t)(nt * 8 + kh * 4 + kt) * 64 + L];
#pragma unroll
                for (int hh = 0; hh < 2; hh++) {
                    int mh = hh * 16;
#pragma unroll
                    for (int kt = 0; kt < 4; kt++) {
                        bf16x8 a = *(const bf16x8*)&sMid[mh + l16][(kh * 4 + kt) * 32 + quad * 8];
                        acc[hh] = __builtin_amdgcn_mfma_f32_16x16x32_bf16(a, b[kt], acc[hh], 0, 0, 0);
                    }
                }
            }
            int c = nt * 16 + l16;
            float sc = g2[c] * rsqrtf(va2[c] + 1e-5f);
            float sh = (b2[c] - mu2[c]) * sc + be2[c];
#pragma unroll
            for (int hh = 0; hh < 2; hh++) {
#pragma unroll
                for (int r = 0; r < 4; r++) {
                    float o = fmaxf(acc[hh][r] * sc + sh, 0.f);
                    sIn[hh * 16 + quad * 4 + r][c] = f2bs(o);
                }
            }
        }
    }
    __syncthreads();

    // ---- coalesced epilogue: hb_out = hb_in + m (16 B/lane streams) ----
    {
        const u16x8* hs8 = (const u16x8*)hb_in;
#pragma unroll
        for (int idx = t; idx < 512; idx += 256) {
            int row = idx >> 4, seg = idx & 15;
            int node = node0 + row;
            if (node < n) {
                u16x8 m = *(const u16x8*)&sIn[row][seg * 8];
                u16x8 s = hs8[(size_t)node * 16 + seg];
                u16x8 o;
#pragma unroll
                for (int j = 0; j < 8; j++)
                    o[j] = f2bs(bs2f(s[j]) + bs2f(m[j]));
                *(u16x8*)(hb_out + (size_t)node * 128 + seg * 8) = o;
            }
        }
    }
}

// ---------------- pooling: run-length over sorted batch (bf16 in) ---------
// 16-node runs -> ~1563 blocks (~6/CU) so the serial load chain is short.
__global__ __launch_bounds__(256) void k_pool(const unsigned short* __restrict__ hb,
                                              const int* __restrict__ batch,
                                              float* __restrict__ pooled, int n)
{
    int c = threadIdx.x & 127;
    int half = threadIdx.x >> 7;
    int base = blockIdx.x * 32 + half * 16;
    float acc = 0.f;
    int curg = -1;
    for (int i = 0; i < 16; i++) {
        int node = base + i;
        if (node >= n) break;
        int g = batch[node];
        if (g != curg) {
            if (curg >= 0) atomicAdd(&pooled[(size_t)curg * 128 + c], acc);
            curg = g;
            acc = 0.f;
        }
        acc += bs2f(hb[(size_t)node * 128 + c]);
    }
    if (curg >= 0) atomicAdd(&pooled[(size_t)curg * 128 + c], acc);
}

__global__ __launch_bounds__(128) void k_head(const float* __restrict__ pooled,
                                              const float* __restrict__ W1,
                                              const float* __restrict__ b1,
                                              const float* __restrict__ W2,
                                              const float* __restrict__ b2,
                                              float* __restrict__ out)
{
    __shared__ float sp[128];
    __shared__ float st[128];
    int t = threadIdx.x;
    int g = blockIdx.x;
    sp[t] = pooled[(size_t)g * 128 + t];
    __syncthreads();
    float a = 0.f;
    for (int k = 0; k < 128; k++) a += sp[k] * W1[k * 128 + t];
    st[t] = fmaxf(a + b1[t], 0.f);
    __syncthreads();
    float o = 0.f;
    for (int k = 0; k < 128; k++) o += st[k] * W2[k * 128 + t];
    out[(size_t)g * 128 + t] = o + b2[t];
}

extern "C" void kernel_launch(void* const* d_in, const int* in_sizes, int n_in,
                              void* d_out, int out_size, void* d_ws, size_t ws_size,
                              hipStream_t stream)
{
    const float* x     = (const float*)d_in[0];
    const int*   ei    = (const int*)d_in[1];
    const int*   batch = (const int*)d_in[2];
    const float* W0    = (const float*)d_in[3];
    const float* b0    = (const float*)d_in[4];
    const float* mlpW1 = (const float*)d_in[5];
    const float* mlpb1 = (const float*)d_in[6];
    const float* bn1g  = (const float*)d_in[7];
    const float* bn1b  = (const float*)d_in[8];
    const float* bn1m  = (const float*)d_in[9];
    const float* bn1v  = (const float*)d_in[10];
    const float* mlpW2 = (const float*)d_in[11];
    const float* mlpb2 = (const float*)d_in[12];
    const float* ng    = (const float*)d_in[13];
    const float* nb    = (const float*)d_in[14];
    const float* nm    = (const float*)d_in[15];
    const float* nv    = (const float*)d_in[16];
    const float* W1    = (const float*)d_in[17];
    const float* b1    = (const float*)d_in[18];
    const float* W2    = (const float*)d_in[19];
    const float* b2    = (const float*)d_in[20];
    float* out = (float*)d_out;

    const int N = in_sizes[0] / 128;
    const int E = in_sizes[1] / 2;
    const int G = out_size / 128;
    const int* srcv = ei;
    const int* dstv = ei + E;

    // workspace layout
    float* pooled = (float*)d_ws;                               // G*128 f32
    unsigned short* hbA = (unsigned short*)(pooled + (size_t)G * 128); // N*128
    unsigned short* hbB = hbA + (size_t)N * 128;                // N*128
    short* pW1 = (short*)(hbB + (size_t)N * 128);               // 4*128*256
    short* pW2 = pW1 + 131072;                                  // 4*256*128
    short* pW0 = pW2 + 131072;                                  // 128*128
    int* ints  = (int*)(pW0 + 16384);
    int* deg      = ints;
    int* rowptr   = ints + N;
    int* cursor   = ints + 2 * N + 1;
    int* partials = ints + 3 * N + 1;                           // 256
    int* adj      = ints + 3 * N + 1 + 256;                     // E

    const int nodeBlocks = (N + 31) / 32;
    const int nbScan = (N + 255) / 256;

    // ---- CSR build + weight packing ----
    hipMemsetAsync(deg, 0, (size_t)N * sizeof(int), stream);
    k_hist<<<(E + 255) / 256, 256, 0, stream>>>(dstv, deg, E);
    k_scanA<<<nbScan, 256, 0, stream>>>(deg, partials, N);
    k_scanC<<<nbScan, 256, 0, stream>>>(deg, partials, rowptr, cursor, N, nbScan);
    k_fill<<<(E + 255) / 256, 256, 0, stream>>>(srcv, dstv, cursor, adj, E);
    k_pack_all<<<(PK1 + PK2 + PK0 + 255) / 256, 256, 0, stream>>>(
        mlpW1, mlpW2, W0, pW1, pW2, pW0);

    // ---- encoder ----
    k_encoder<<<nodeBlocks, 256, 0, stream>>>(x, pW0, b0, hbA, N);

    // ---- layers: fused gather+MLP, ping-pong hbA/hbB ----
    unsigned short* hc = hbA;
    unsigned short* hn = hbB;
    for (int l = 0; l < 4; l++) {
        k_layer<<<nodeBlocks, 256, 0, stream>>>(
            hc, hn, rowptr, adj,
            pW1 + (size_t)l * 32768, mlpb1 + (size_t)l * 256,
            bn1g + (size_t)l * 256, bn1b + (size_t)l * 256,
            bn1m + (size_t)l * 256, bn1v + (size_t)l * 256,
            pW2 + (size_t)l * 32768, mlpb2 + (size_t)l * 128,
            ng + (size_t)l * 128, nb + (size_t)l * 128,
            nm + (size_t)l * 128, nv + (size_t)l * 128,
            N);
        unsigned short* tmp = hc; hc = hn; hn = tmp;
    }

    // ---- pool + head ----
    hipMemsetAsync(pooled, 0, (size_t)G * 128 * sizeof(float), stream);
    k_pool<<<(N + 31) / 32, 256, 0, stream>>>(hc, batch, pooled, N);
    k_head<<<G, 128, 0, stream>>>(pooled, W1, b1, W2, b2, out);
}

// Round 4
// 357.442 us; speedup vs baseline: 1.6042x; 1.0650x over previous
//
#include <hip/hip_runtime.h>
#include <hip/hip_bf16.h>

// ---------------------------------------------------------------------------
// GIN encoder. Residual stream in bf16 only (ping-pong A/B).
// Fused per-layer kernel (k_layer): gather + MLP + residual.
// Round 4: gather restructured to FOUR static streams per wave in TWO
// episodes (rows ep*4+{0..3}); consecutive nodes share CSR bounds so one
// up-front rowptr[base..base+8] read feeds all streams. 8 rows in flight
// per wave, half the episode startups. VGPR ~90 -> __launch_bounds__(256,4)
// (VGPR granule is 64: anything >64 caps at 4 waves/SIMD regardless).
// Freed LDS spent on sSelf: epilogue reads the residual from LDS instead
// of re-reading hb_in from global (-12.8 MB fetch per layer).
// ---------------------------------------------------------------------------

typedef short bf16x8 __attribute__((ext_vector_type(8)));
typedef unsigned short u16x8 __attribute__((ext_vector_type(8)));
typedef float f32x4 __attribute__((ext_vector_type(4)));

__device__ __forceinline__ float bs2f(unsigned short u) {
    return __uint_as_float(((unsigned)u) << 16);
}
__device__ __forceinline__ unsigned short f2bs(float f) {
    __hip_bfloat16 h = __float2bfloat16(f);
    return *reinterpret_cast<unsigned short*>(&h);
}

// masked packed unpack-accumulate: msk=~0u accumulates, 0u adds +0.0f
__device__ __forceinline__ void accm(float* acc, u16x8 v, unsigned msk) {
    union { u16x8 u; unsigned int w[4]; } cv;
    cv.u = v;
#pragma unroll
    for (int k = 0; k < 4; k++) {
        unsigned int d = cv.w[k] & msk;
        acc[2 * k]     += __uint_as_float(d << 16);
        acc[2 * k + 1] += __uint_as_float(d & 0xffff0000u);
    }
}

// ---------------- CSR build ----------------
__global__ __launch_bounds__(256) void k_hist(const int* __restrict__ dst,
                                              int* __restrict__ deg, int nE)
{
    int i = blockIdx.x * 256 + threadIdx.x;
    if (i < nE) atomicAdd(&deg[dst[i]], 1);
}

__global__ __launch_bounds__(256) void k_scanA(const int* __restrict__ deg,
                                               int* __restrict__ partials, int n)
{
    int i = blockIdx.x * 256 + threadIdx.x;
    int v = (i < n) ? deg[i] : 0;
#pragma unroll
    for (int off = 32; off >= 1; off >>= 1) v += __shfl_down(v, off, 64);
    __shared__ int ws[4];
    int wave = threadIdx.x >> 6;
    if ((threadIdx.x & 63) == 0) ws[wave] = v;
    __syncthreads();
    if (threadIdx.x == 0)
        partials[blockIdx.x] = ws[0] + ws[1] + ws[2] + ws[3];
}

__global__ __launch_bounds__(256) void k_scanC(const int* __restrict__ deg,
                                               const int* __restrict__ partials,
                                               int* __restrict__ rowptr,
                                               int* __restrict__ cursor,
                                               int n, int nb)
{
    __shared__ int sp[256];
    __shared__ int s[256];
    int t = threadIdx.x;
    int pv = (t < nb) ? partials[t] : 0;
    sp[t] = pv;
    __syncthreads();
    for (int off = 1; off < 256; off <<= 1) {
        int u = (t >= off) ? sp[t - off] : 0;
        __syncthreads();
        sp[t] += u;
        __syncthreads();
    }
    int base = (blockIdx.x == 0) ? 0 : sp[blockIdx.x - 1];
    int i = blockIdx.x * 256 + t;
    int v = (i < n) ? deg[i] : 0;
    s[t] = v;
    __syncthreads();
    for (int off = 1; off < 256; off <<= 1) {
        int u = (t >= off) ? s[t - off] : 0;
        __syncthreads();
        s[t] += u;
        __syncthreads();
    }
    int inc = s[t];
    if (i < n) {
        int ex = base + inc - v;
        rowptr[i] = ex;
        cursor[i] = ex;
        if (i == n - 1) rowptr[n] = base + inc;
    }
}

__global__ __launch_bounds__(256) void k_fill(const int* __restrict__ src,
                                              const int* __restrict__ dst,
                                              int* __restrict__ cursor,
                                              int* __restrict__ adj, int nE)
{
    int i = blockIdx.x * 256 + threadIdx.x;
    if (i < nE) {
        int pos = atomicAdd(&cursor[dst[i]], 1);
        adj[pos] = src[i];
    }
}

// ---------------- weight packing (all weights, one launch) ----------------
__device__ __forceinline__ void pack_one(const float* __restrict__ W,
                                         short* __restrict__ P,
                                         int id, int Kt, int Nt)
{
    int lane = id & 63;
    int t = id >> 6;
    int kt = t % Kt; t /= Kt;
    int nt = t % Nt; int l = t / Nt;
    int K = Kt * 32, N = Nt * 16;
    const float* Wl = W + (size_t)l * K * N;
    int n = nt * 16 + (lane & 15);
    int kbase = kt * 32 + (lane >> 4) * 8;
    bf16x8 v;
#pragma unroll
    for (int j = 0; j < 8; j++)
        v[j] = (short)f2bs(Wl[(size_t)(kbase + j) * N + n]);
    *(bf16x8*)(P + (size_t)id * 8) = v;
}

#define PK1 16384   // 4 layers * Nt16 * Kt4 * 64
#define PK2 16384   // 4 layers * Nt8  * Kt8 * 64
#define PK0 2048    // 1 layer  * Nt8  * Kt4 * 64

__global__ __launch_bounds__(256) void k_pack_all(
    const float* __restrict__ mlpW1, const float* __restrict__ mlpW2,
    const float* __restrict__ W0,
    short* __restrict__ pW1, short* __restrict__ pW2, short* __restrict__ pW0)
{
    int id = blockIdx.x * 256 + threadIdx.x;
    if (id < PK1) {
        pack_one(mlpW1, pW1, id, 4, 16);
    } else if (id < PK1 + PK2) {
        pack_one(mlpW2, pW2, id - PK1, 8, 8);
    } else if (id < PK1 + PK2 + PK0) {
        pack_one(W0, pW0, id - PK1 - PK2, 4, 8);
    }
}

// ---------------- encoder: hb = bf16(x@W0 + b0) via MFMA ------------------
__global__ __launch_bounds__(256) void k_encoder(const float* __restrict__ x,
                                                 const short* __restrict__ pW0,
                                                 const float* __restrict__ b0,
                                                 unsigned short* __restrict__ hb,
                                                 int n)
{
    __shared__ unsigned short sX[32][136];
    const int t = threadIdx.x;
    const int w = t >> 6;
    const int L = t & 63;
    const int node0 = blockIdx.x * 32;

    const float4* x4 = (const float4*)x;
    for (int i = t; i < 32 * 32; i += 256) {
        int m = i >> 5, cgi = i & 31;
        int node = node0 + m;
        float4 v = make_float4(0.f, 0.f, 0.f, 0.f);
        if (node < n) v = x4[(size_t)node * 32 + cgi];
        ushort4 p;
        p.x = f2bs(v.x); p.y = f2bs(v.y); p.z = f2bs(v.z); p.w = f2bs(v.w);
        *(ushort4*)&sX[m][cgi * 4] = p;
    }
    __syncthreads();

    const int quad = L >> 4;
    const int l16 = L & 15;
    const bf16x8* base = (const bf16x8*)pW0;

#pragma unroll
    for (int jj = 0; jj < 2; jj++) {
        int nt = w * 2 + jj;
        bf16x8 b[4];
#pragma unroll
        for (int kt = 0; kt < 4; kt++)
            b[kt] = base[(size_t)(nt * 4 + kt) * 64 + L];
        int c = nt * 16 + l16;
        float bc = b0[c];
#pragma unroll
        for (int hh = 0; hh < 2; hh++) {
            int mh = hh * 16;
            f32x4 acc = {0.f, 0.f, 0.f, 0.f};
#pragma unroll
            for (int kt = 0; kt < 4; kt++) {
                bf16x8 a = *(const bf16x8*)&sX[mh + l16][kt * 32 + quad * 8];
                acc = __builtin_amdgcn_mfma_f32_16x16x32_bf16(a, b[kt], acc, 0, 0, 0);
            }
#pragma unroll
            for (int r = 0; r < 4; r++) {
                int node = node0 + mh + quad * 4 + r;
                if (node < n)
                    hb[(size_t)node * 128 + c] = f2bs(acc[r] + bc);
            }
        }
    }
}

// ---------------- fused layer: gather + MLP + residual --------------------
// hb_out = hb_in + relu(BN2(W2 relu(BN1(W1 (hb_in + sum_neighbors)))))
// Gather: 4 static streams/wave (rows ep*4+{0..3}) x 2 episodes, clamped+
// masked 4-edge chunks (unroll-2 per stream), adj prefetched one chunk
// ahead. Lane layout: g = L>>4 picks 1 of 4 edges in the chunk, l16 = L&15
// is the 16B channel segment; 16 lanes cover one 256B node row.
__global__ __launch_bounds__(256, 4) void k_layer(
    const unsigned short* __restrict__ hb_in,
    unsigned short* __restrict__ hb_out,
    const int* __restrict__ rowptr, const int* __restrict__ adj,
    const short* __restrict__ pW1, const float* __restrict__ b1,
    const float* __restrict__ g1, const float* __restrict__ be1,
    const float* __restrict__ mu1, const float* __restrict__ va1,
    const short* __restrict__ pW2, const float* __restrict__ b2,
    const float* __restrict__ g2, const float* __restrict__ be2,
    const float* __restrict__ mu2, const float* __restrict__ va2,
    int n)
{
    __shared__ unsigned short sIn[32][136];    // gathered agg; reused for m out
    __shared__ unsigned short sMid[32][264];   // bf16 MLP hidden, pad 8
    __shared__ unsigned short sSelf[32][136];  // residual rows for epilogue
    const int t = threadIdx.x;
    const int w = t >> 6;
    const int L = t & 63;
    const int node0 = blockIdx.x * 32;
    const int g = L >> 4;
    const int l16 = L & 15;
    const int wrow = w * 8;

    // ---- gather phase: wave w fills sIn/sSelf rows wrow..wrow+7 ----
    {
        const u16x8* hb8 = (const u16x8*)hb_in;
        const int base = node0 + wrow;

        // rowptr[base .. base+8], index-clamped so OOB rows degenerate
        // to empty ranges (rowptr[n] repeated).
        int rp[9];
#pragma unroll
        for (int j = 0; j < 9; j++) {
            int idx = base + j;
            rp[j] = rowptr[idx > n ? n : idx];
        }

#define CHUNK_INIT(S, EE, QQ)                                               \
        int e##S = (EE), q##S = (QQ);                                       \
        bool ok##S = e##S < q##S;                                           \
        int x##S##0 = e##S + g, x##S##1 = e##S + 4 + g;                     \
        int i##S##0 = adj[ok##S ? (x##S##0 < q##S ? x##S##0 : q##S - 1) : 0]; \
        int i##S##1 = adj[ok##S ? (x##S##1 < q##S ? x##S##1 : q##S - 1) : 0]; \
        float acc##S[8] = {0.f,0.f,0.f,0.f,0.f,0.f,0.f,0.f};

#define CHUNK_LOAD(S)                                                       \
        u16x8 r##S##0 = hb8[(unsigned)i##S##0 * 16u + l16];                 \
        u16x8 r##S##1 = hb8[(unsigned)i##S##1 * 16u + l16];

#define CHUNK_MASK(S)                                                       \
        unsigned m##S##0 = (ok##S && e##S + g < q##S)     ? ~0u : 0u;       \
        unsigned m##S##1 = (ok##S && e##S + 4 + g < q##S) ? ~0u : 0u;

#define CHUNK_PREF(S)                                                       \
        int ne##S = ok##S ? e##S + 8 : e##S;                                \
        bool nok##S = ne##S < q##S;                                         \
        int nx##S##0 = ne##S + g, nx##S##1 = ne##S + 4 + g;                 \
        int ni##S##0 = adj[nok##S ? (nx##S##0 < q##S ? nx##S##0 : q##S - 1) : 0]; \
        int ni##S##1 = adj[nok##S ? (nx##S##1 < q##S ? nx##S##1 : q##S - 1) : 0];

#define CHUNK_ACC(S)                                                        \
        accm(acc##S, r##S##0, m##S##0);                                     \
        accm(acc##S, r##S##1, m##S##1);

#define CHUNK_ROT(S)                                                        \
        e##S = ne##S; ok##S = nok##S; i##S##0 = ni##S##0; i##S##1 = ni##S##1;

#define SELF_LOAD(S, NODE)                                                  \
        u16x8 self##S;                                                      \
        {                                                                   \
            _Pragma("unroll")                                               \
            for (int j = 0; j < 8; j++) self##S[j] = 0;                     \
            if ((NODE) < n) self##S = hb8[(unsigned)(NODE) * 16u + l16];    \
        }

#define STREAM_FIN(S, ROWIDX)                                               \
        {                                                                   \
            u16x8 o;                                                        \
            _Pragma("unroll")                                               \
            for (int j = 0; j < 8; j++) {                                   \
                float vv = acc##S[j];                                       \
                vv += __shfl_xor(vv, 16, 64);                               \
                vv += __shfl_xor(vv, 32, 64);                               \
                o[j] = f2bs(vv + bs2f(self##S[j]));                         \
            }                                                               \
            if (g == 0) *(u16x8*)&sIn[(ROWIDX)][l16 * 8] = o;               \
            if (g == 1) *(u16x8*)&sSelf[(ROWIDX)][l16 * 8] = self##S;       \
        }

#pragma unroll
        for (int ep = 0; ep < 2; ep++) {
            const int r0 = ep * 4;
            CHUNK_INIT(A, rp[r0 + 0], rp[r0 + 1])
            CHUNK_INIT(B, rp[r0 + 1], rp[r0 + 2])
            CHUNK_INIT(C, rp[r0 + 2], rp[r0 + 3])
            CHUNK_INIT(D, rp[r0 + 3], rp[r0 + 4])

            while (okA | okB | okC | okD) {
                CHUNK_LOAD(A) CHUNK_LOAD(B) CHUNK_LOAD(C) CHUNK_LOAD(D)
                CHUNK_MASK(A) CHUNK_MASK(B) CHUNK_MASK(C) CHUNK_MASK(D)
                CHUNK_PREF(A) CHUNK_PREF(B) CHUNK_PREF(C) CHUNK_PREF(D)
                CHUNK_ACC(A) CHUNK_ACC(B) CHUNK_ACC(C) CHUNK_ACC(D)
                CHUNK_ROT(A) CHUNK_ROT(B) CHUNK_ROT(C) CHUNK_ROT(D)
            }

            SELF_LOAD(A, base + r0 + 0)
            SELF_LOAD(B, base + r0 + 1)
            SELF_LOAD(C, base + r0 + 2)
            SELF_LOAD(D, base + r0 + 3)
            STREAM_FIN(A, wrow + r0 + 0)
            STREAM_FIN(B, wrow + r0 + 1)
            STREAM_FIN(C, wrow + r0 + 2)
            STREAM_FIN(D, wrow + r0 + 3)
        }
#undef CHUNK_INIT
#undef CHUNK_LOAD
#undef CHUNK_MASK
#undef CHUNK_PREF
#undef CHUNK_ACC
#undef CHUNK_ROT
#undef SELF_LOAD
#undef STREAM_FIN
    }
    __syncthreads();

    const int quad = L >> 4;

    // ---- phase 1: sMid = relu(BN1(sIn @ W1 + b1)), 32x256, K=128 ----
    {
        const bf16x8* base1 = (const bf16x8*)pW1;
#pragma unroll
        for (int j = 0; j < 4; j++) {
            int nt = w * 4 + j;
            bf16x8 b[4];
#pragma unroll
            for (int kt = 0; kt < 4; kt++)
                b[kt] = base1[(size_t)(nt * 4 + kt) * 64 + L];
            int c = nt * 16 + l16;
            float sc = g1[c] * rsqrtf(va1[c] + 1e-5f);
            float sh = (b1[c] - mu1[c]) * sc + be1[c];
#pragma unroll
            for (int hh = 0; hh < 2; hh++) {
                int mh = hh * 16;
                f32x4 acc = {0.f, 0.f, 0.f, 0.f};
#pragma unroll
                for (int kt = 0; kt < 4; kt++) {
                    bf16x8 a = *(const bf16x8*)&sIn[mh + l16][kt * 32 + quad * 8];
                    acc = __builtin_amdgcn_mfma_f32_16x16x32_bf16(a, b[kt], acc, 0, 0, 0);
                }
#pragma unroll
                for (int r = 0; r < 4; r++) {
                    float v = fmaxf(acc[r] * sc + sh, 0.f);
                    sMid[mh + quad * 4 + r][c] = f2bs(v);
                }
            }
        }
    }
    __syncthreads();

    // ---- phase 2: m = relu(BN2(sMid @ W2 + b2)) -> staged into sIn ----
    {
        const bf16x8* base2 = (const bf16x8*)pW2;
#pragma unroll
        for (int jj = 0; jj < 2; jj++) {
            int nt = w * 2 + jj;
            f32x4 acc[2];
            acc[0] = (f32x4){0.f, 0.f, 0.f, 0.f};
            acc[1] = (f32x4){0.f, 0.f, 0.f, 0.f};
#pragma unroll
            for (int kh = 0; kh < 2; kh++) {
                bf16x8 b[4];
#pragma unroll
                for (int kt = 0; kt < 4; kt++)
                    b[kt] = base2[(size_t)(nt * 8 + kh * 4 + kt) * 64 + L];
#pragma unroll
                for (int hh = 0; hh < 2; hh++) {
                    int mh = hh * 16;
#pragma unroll
                    for (int kt = 0; kt < 4; kt++) {
                        bf16x8 a = *(const bf16x8*)&sMid[mh + l16][(kh * 4 + kt) * 32 + quad * 8];
                        acc[hh] = __builtin_amdgcn_mfma_f32_16x16x32_bf16(a, b[kt], acc[hh], 0, 0, 0);
                    }
                }
            }
            int c = nt * 16 + l16;
            float sc = g2[c] * rsqrtf(va2[c] + 1e-5f);
            float sh = (b2[c] - mu2[c]) * sc + be2[c];
#pragma unroll
            for (int hh = 0; hh < 2; hh++) {
#pragma unroll
                for (int r = 0; r < 4; r++) {
                    float o = fmaxf(acc[hh][r] * sc + sh, 0.f);
                    sIn[hh * 16 + quad * 4 + r][c] = f2bs(o);
                }
            }
        }
    }
    __syncthreads();

    // ---- coalesced epilogue: hb_out = sSelf + m (16 B/lane streams) ----
    {
#pragma unroll
        for (int idx = t; idx < 512; idx += 256) {
            int row = idx >> 4, seg = idx & 15;
            int node = node0 + row;
            if (node < n) {
                u16x8 m = *(const u16x8*)&sIn[row][seg * 8];
                u16x8 s = *(const u16x8*)&sSelf[row][seg * 8];
                u16x8 o;
#pragma unroll
                for (int j = 0; j < 8; j++)
                    o[j] = f2bs(bs2f(s[j]) + bs2f(m[j]));
                *(u16x8*)(hb_out + (size_t)node * 128 + seg * 8) = o;
            }
        }
    }
}

// ---------------- pooling: run-length over sorted batch (bf16 in) ---------
// 16-node runs -> ~1563 blocks (~6/CU) so the serial load chain is short.
__global__ __launch_bounds__(256) void k_pool(const unsigned short* __restrict__ hb,
                                              const int* __restrict__ batch,
                                              float* __restrict__ pooled, int n)
{
    int c = threadIdx.x & 127;
    int half = threadIdx.x >> 7;
    int base = blockIdx.x * 32 + half * 16;
    float acc = 0.f;
    int curg = -1;
    for (int i = 0; i < 16; i++) {
        int node = base + i;
        if (node >= n) break;
        int g = batch[node];
        if (g != curg) {
            if (curg >= 0) atomicAdd(&pooled[(size_t)curg * 128 + c], acc);
            curg = g;
            acc = 0.f;
        }
        acc += bs2f(hb[(size_t)node * 128 + c]);
    }
    if (curg >= 0) atomicAdd(&pooled[(size_t)curg * 128 + c], acc);
}

__global__ __launch_bounds__(128) void k_head(const float* __restrict__ pooled,
                                              const float* __restrict__ W1,
                                              const float* __restrict__ b1,
                                              const float* __restrict__ W2,
                                              const float* __restrict__ b2,
                                              float* __restrict__ out)
{
    __shared__ float sp[128];
    __shared__ float st[128];
    int t = threadIdx.x;
    int g = blockIdx.x;
    sp[t] = pooled[(size_t)g * 128 + t];
    __syncthreads();
    float a = 0.f;
    for (int k = 0; k < 128; k++) a += sp[k] * W1[k * 128 + t];
    st[t] = fmaxf(a + b1[t], 0.f);
    __syncthreads();
    float o = 0.f;
    for (int k = 0; k < 128; k++) o += st[k] * W2[k * 128 + t];
    out[(size_t)g * 128 + t] = o + b2[t];
}

extern "C" void kernel_launch(void* const* d_in, const int* in_sizes, int n_in,
                              void* d_out, int out_size, void* d_ws, size_t ws_size,
                              hipStream_t stream)
{
    const float* x     = (const float*)d_in[0];
    const int*   ei    = (const int*)d_in[1];
    const int*   batch = (const int*)d_in[2];
    const float* W0    = (const float*)d_in[3];
    const float* b0    = (const float*)d_in[4];
    const float* mlpW1 = (const float*)d_in[5];
    const float* mlpb1 = (const float*)d_in[6];
    const float* bn1g  = (const float*)d_in[7];
    const float* bn1b  = (const float*)d_in[8];
    const float* bn1m  = (const float*)d_in[9];
    const float* bn1v  = (const float*)d_in[10];
    const float* mlpW2 = (const float*)d_in[11];
    const float* mlpb2 = (const float*)d_in[12];
    const float* ng    = (const float*)d_in[13];
    const float* nb    = (const float*)d_in[14];
    const float* nm    = (const float*)d_in[15];
    const float* nv    = (const float*)d_in[16];
    const float* W1    = (const float*)d_in[17];
    const float* b1    = (const float*)d_in[18];
    const float* W2    = (const float*)d_in[19];
    const float* b2    = (const float*)d_in[20];
    float* out = (float*)d_out;

    const int N = in_sizes[0] / 128;
    const int E = in_sizes[1] / 2;
    const int G = out_size / 128;
    const int* srcv = ei;
    const int* dstv = ei + E;

    // workspace layout
    float* pooled = (float*)d_ws;                               // G*128 f32
    unsigned short* hbA = (unsigned short*)(pooled + (size_t)G * 128); // N*128
    unsigned short* hbB = hbA + (size_t)N * 128;                // N*128
    short* pW1 = (short*)(hbB + (size_t)N * 128);               // 4*128*256
    short* pW2 = pW1 + 131072;                                  // 4*256*128
    short* pW0 = pW2 + 131072;                                  // 128*128
    int* ints  = (int*)(pW0 + 16384);
    int* deg      = ints;
    int* rowptr   = ints + N;
    int* cursor   = ints + 2 * N + 1;
    int* partials = ints + 3 * N + 1;                           // 256
    int* adj      = ints + 3 * N + 1 + 256;                     // E

    const int nodeBlocks = (N + 31) / 32;
    const int nbScan = (N + 255) / 256;

    // ---- CSR build + weight packing ----
    hipMemsetAsync(deg, 0, (size_t)N * sizeof(int), stream);
    k_hist<<<(E + 255) / 256, 256, 0, stream>>>(dstv, deg, E);
    k_scanA<<<nbScan, 256, 0, stream>>>(deg, partials, N);
    k_scanC<<<nbScan, 256, 0, stream>>>(deg, partials, rowptr, cursor, N, nbScan);
    k_fill<<<(E + 255) / 256, 256, 0, stream>>>(srcv, dstv, cursor, adj, E);
    k_pack_all<<<(PK1 + PK2 + PK0 + 255) / 256, 256, 0, stream>>>(
        mlpW1, mlpW2, W0, pW1, pW2, pW0);

    // ---- encoder ----
    k_encoder<<<nodeBlocks, 256, 0, stream>>>(x, pW0, b0, hbA, N);

    // ---- layers: fused gather+MLP, ping-pong hbA/hbB ----
    unsigned short* hc = hbA;
    unsigned short* hn = hbB;
    for (int l = 0; l < 4; l++) {
        k_layer<<<nodeBlocks, 256, 0, stream>>>(
            hc, hn, rowptr, adj,
            pW1 + (size_t)l * 32768, mlpb1 + (size_t)l * 256,
            bn1g + (size_t)l * 256, bn1b + (size_t)l * 256,
            bn1m + (size_t)l * 256, bn1v + (size_t)l * 256,
            pW2 + (size_t)l * 32768, mlpb2 + (size_t)l * 128,
            ng + (size_t)l * 128, nb + (size_t)l * 128,
            nm + (size_t)l * 128, nv + (size_t)l * 128,
            N);
        unsigned short* tmp = hc; hc = hn; hn = tmp;
    }

    // ---- pool + head ----
    hipMemsetAsync(pooled, 0, (size_t)G * 128 * sizeof(float), stream);
    k_pool<<<(N + 31) / 32, 256, 0, stream>>>(hc, batch, pooled, N);
    k_head<<<G, 128, 0, stream>>>(pooled, W1, b1, W2, b2, out);
}